// Round 7
// baseline (592.022 us; speedup 1.0000x reference)
//
#include <hip/hip_runtime.h>

#define BSZ 16384

typedef __attribute__((ext_vector_type(8))) short bf16x8;
typedef __attribute__((ext_vector_type(4))) float f32x4;
typedef __attribute__((ext_vector_type(8))) unsigned short u16x8;

// pack fp32 -> interleaved (hi bf16 | lo bf16 << 16); hi+lo ~= x within 2^-16 rel
__device__ inline unsigned packbf(float v) {
    unsigned u = __float_as_uint(v);
    unsigned r = u + (0x7fffu + ((u >> 16) & 1u));
    unsigned hi = r >> 16;
    float rem = v - __uint_as_float(r & 0xffff0000u);
    unsigned lu = __float_as_uint(rem);
    unsigned lo = (lu + (0x7fffu + ((lu >> 16) & 1u))) >> 16;
    return hi | (lo << 16);
}
__device__ inline float unpackf(unsigned u) {
    return __uint_as_float(u << 16) + __uint_as_float(u & 0xffff0000u);
}
// 8 interleaved elems (two uint4) -> hi-plane and lo-plane bf16x8 frags
__device__ inline void unpack8(const uint4 p0, const uint4 p1, bf16x8& hi, bf16x8& lo) {
    union { unsigned u[4]; bf16x8 v; } H, L;
    H.u[0] = __builtin_amdgcn_perm(p0.y, p0.x, 0x05040100u);
    H.u[1] = __builtin_amdgcn_perm(p0.w, p0.z, 0x05040100u);
    H.u[2] = __builtin_amdgcn_perm(p1.y, p1.x, 0x05040100u);
    H.u[3] = __builtin_amdgcn_perm(p1.w, p1.z, 0x05040100u);
    L.u[0] = __builtin_amdgcn_perm(p0.y, p0.x, 0x07060302u);
    L.u[1] = __builtin_amdgcn_perm(p0.w, p0.z, 0x07060302u);
    L.u[2] = __builtin_amdgcn_perm(p1.y, p1.x, 0x07060302u);
    L.u[3] = __builtin_amdgcn_perm(p1.w, p1.z, 0x07060302u);
    hi = H.v; lo = L.v;
}

// ---------------- prep: fp32 -> interleaved planes (codebooks only now) --------
struct PrepArgs {
    const float* src[24];
    unsigned* dst[24];
    int start[24];   // prefix (elements); all sizes multiples of 1024
    int nseg;
};
__global__ __launch_bounds__(256) void prep_kernel(PrepArgs pa) {
    const int base = blockIdx.x << 10;
    int seg = 0;
    #pragma unroll 1
    for (int i = 0; i < 23; ++i)
        if (seg + 1 < pa.nseg && base >= pa.start[seg + 1]) seg++;
    const int off = base - pa.start[seg] + (threadIdx.x << 2);
    const float4 v = *(const float4*)(pa.src[seg] + off);
    uint4 u;
    u.x = packbf(v.x); u.y = packbf(v.y); u.z = packbf(v.z); u.w = packbf(v.w);
    *(uint4*)(pa.dst[seg] + off) = u;
}

// ---------------- codebook norms (all 3 levels, fp32 inputs) ----------------
__global__ __launch_bounds__(256) void cb_norms3(
    const float* __restrict__ c0, const float* __restrict__ c1,
    const float* __restrict__ c2, float* __restrict__ cbn)
{
    const int r = blockIdx.x * 256 + threadIdx.x;   // 0..10239
    const float* src; int off;
    if (r < 2048) { src = c0; off = r; }
    else if (r < 6144) { src = c1; off = r - 2048; }
    else { src = c2; off = r - 6144; }
    const float4* p = (const float4*)(src + (size_t)off * 64);
    float s = 0.f;
    #pragma unroll
    for (int c = 0; c < 16; ++c) {
        float4 v = p[c];
        s += v.x * v.x + v.y * v.y + v.z * v.z + v.w * v.w;
    }
    cbn[r] = s;
}

// ---------------- codebook -> MFMA-fragment-ordered split bf16 planes ----------
__global__ __launch_bounds__(256) void cb_frag3(
    const float* __restrict__ c0, const float* __restrict__ c1,
    const float* __restrict__ c2, unsigned short* __restrict__ f0,
    unsigned short* __restrict__ f1, unsigned short* __restrict__ f2)
{
    int g = blockIdx.x * 256 + threadIdx.x;   // 0 .. 10240*16
    const float* src; unsigned short* dst;
    if (g < 32768) { src = c0; dst = f0; }
    else if (g < 98304) { src = c1; dst = f1; g -= 32768; }
    else { src = c2; dst = f2; g -= 98304; }
    const int l = g & 63;
    const int fr = g >> 6;
    const int t = fr >> 2, ks = (fr >> 1) & 1, pln = fr & 1;
    const int e = t * 16 + (l & 15);
    const int d0 = ks * 32 + (l >> 4) * 8;
    const float* s = src + (size_t)e * 64 + d0;
    union { unsigned short o[8]; u16x8 v; } U;
    #pragma unroll
    for (int j = 0; j < 8; ++j) {
        const float v = s[j];
        const unsigned u = __float_as_uint(v);
        const unsigned r = u + (0x7fffu + ((u >> 16) & 1u));
        if (pln == 0) {
            U.o[j] = (unsigned short)(r >> 16);
        } else {
            const float rem = v - __uint_as_float(r & 0xffff0000u);
            const unsigned lu = __float_as_uint(rem);
            U.o[j] = (unsigned short)((lu + (0x7fffu + ((lu >> 16) & 1u))) >> 16);
        }
    }
    *(u16x8*)(dst + (size_t)g * 8) = U.v;
}

// ---------------- weights -> MFMA-fragment-ordered split bf16 planes ----------
// frame f = (nt*(K/32)+ks)*2+p, lane l holds entry n = nt*16+(l&15),
// dims d0 = ks*32+(l>>4)*8.  Slots per segment = N*K/4 (TWO planes).
struct WFragArgs {
    const float* src[18];
    unsigned short* dst[18];
    int start[19];   // prefix in lane-slots (elems*2/8)
    int kslog[18];   // log2(K/32)
};
__global__ __launch_bounds__(256) void w_frag(WFragArgs wa) {
    const int gid = blockIdx.x * 256 + threadIdx.x;
    int seg = 0;
    #pragma unroll 1
    for (int i = 0; i < 17; ++i)
        if (gid >= wa.start[seg + 1]) seg++;
    const int s = gid - wa.start[seg];
    const int l = s & 63, fr = s >> 6;
    const int kl = wa.kslog[seg];
    const int pln = fr & 1;
    const int ks = (fr >> 1) & ((1 << kl) - 1);
    const int nt = fr >> (1 + kl);
    const int K = 32 << kl;
    const int n = nt * 16 + (l & 15);
    const int d0 = ks * 32 + (l >> 4) * 8;
    const float* sp = wa.src[seg] + (size_t)n * K + d0;
    union { unsigned short o[8]; u16x8 v; } U;
    #pragma unroll
    for (int j = 0; j < 8; ++j) {
        const float v = sp[j];
        const unsigned u = __float_as_uint(v);
        const unsigned r = u + (0x7fffu + ((u >> 16) & 1u));
        if (pln == 0) {
            U.o[j] = (unsigned short)(r >> 16);
        } else {
            const float rem = v - __uint_as_float(r & 0xffff0000u);
            const unsigned lu = __float_as_uint(rem);
            U.o[j] = (unsigned short)((lu + (0x7fffu + ((lu >> 16) & 1u))) >> 16);
        }
    }
    *(u16x8*)(wa.dst[seg] + (size_t)s * 8) = U.v;
}

// ---------------- attention fold: W_comb = ow@wv (FRAGGED planes) ----------------
__global__ __launch_bounds__(256) void attn_combine(
    const float* __restrict__ iw, const float* __restrict__ ib,
    const float* __restrict__ ow, const float* __restrict__ ob,
    unsigned* __restrict__ wcomb, float* __restrict__ bcomb)
{
    __shared__ float o[4096], v[4096];
    const float* wv = iw + 128 * 64;
    for (int t = threadIdx.x; t < 4096; t += 256) { o[t] = ow[t]; v[t] = wv[t]; }
    __syncthreads();
    unsigned short* wc = (unsigned short*)wcomb;
    for (int t = threadIdx.x; t < 4096; t += 256) {
        const int j = t >> 6, i = t & 63;   // j = out dim (n), i = in dim (k)
        float s = 0.f;
        #pragma unroll
        for (int k = 0; k < 64; ++k) s += o[j * 64 + k] * v[k * 64 + i];
        const unsigned u = __float_as_uint(s);
        const unsigned r = u + (0x7fffu + ((u >> 16) & 1u));
        const unsigned short hi = (unsigned short)(r >> 16);
        const float rem = s - __uint_as_float(r & 0xffff0000u);
        const unsigned lu = __float_as_uint(rem);
        const unsigned short lo = (unsigned short)((lu + (0x7fffu + ((lu >> 16) & 1u))) >> 16);
        const int nt = j >> 4, ks = i >> 5;
        const int lsub = (j & 15) | (((i >> 3) & 3) << 4);
        const int e = i & 7;
        wc[(size_t)((nt * 2 + ks) * 2 + 0) * 512 + lsub * 8 + e] = hi;
        wc[(size_t)((nt * 2 + ks) * 2 + 1) * 512 + lsub * 8 + e] = lo;
    }
    if (threadIdx.x < 64) {
        const int j = threadIdx.x;
        const float* bv = ib + 128;
        float s = ob[j];
        #pragma unroll
        for (int k = 0; k < 64; ++k) s += o[j * 64 + k] * bv[k];
        bcomb[j] = s;
    }
}

// ---------------- batched MFMA GEMM v5: dbuf A-LDS, lgkm-only barrier ---------
// Same data path as the passing gemmb4 (interleaved stride-36 A-LDS, unpack8
// reads, fragged-W direct B, identical MFMA order). Sync restructured: 2 LDS
// buffers, ONE `s_waitcnt lgkmcnt(0); s_barrier` per K-step — vmcnt is never
// drained at a barrier, so A(t+1)/A(t+2) HBM prefetches and B(t+1) L2 loads
// stay in flight across it. Per-wave DS ops drain via lgkmcnt before each
// barrier => cross-wave buffer hand-off is race-free.
struct GemmB {
    const void* A[3];
    const unsigned short* W[3];
    const float* bias[3];
    void* C[3];
};
template<int SPLIT, int BN, int A_F32, int OUTP>
__global__ __launch_bounds__(256) void gemmb5(
    GemmB g, int M, int N, int K, int relu)
{
    constexpr int NT = BN / 32;
    __shared__ unsigned Asm[2][128 * 36];
    const int z = blockIdx.z;
    const void* Ap_ = g.A[z];
    const unsigned short* Wf = g.W[z];
    const float* bias = g.bias[z];
    void* Cp = g.C[z];
    const int tid = threadIdx.x;
    const int m0 = blockIdx.y << 7;
    const int n0 = blockIdx.x * BN;
    const int lane = tid & 63, wv = tid >> 6;
    const int wm = wv >> 1, wn = wv & 1;
    const int q = lane >> 4, c16 = lane & 15;
    const int nk = K >> 5;

    f32x4 acc[4][NT] = {};

    uint4 rA[4];
    auto ldA = [&](int k0) {
        #pragma unroll
        for (int i = 0; i < 4; ++i) {
            const int c = tid + (i << 8);
            const int row = c >> 3, col = (c & 7) << 2;
            rA[i] = *(const uint4*)((const unsigned*)Ap_ + (size_t)(m0 + row) * K + k0 + col);
        }
    };
    auto stA = [&](int p) {
        #pragma unroll
        for (int i = 0; i < 4; ++i) {
            const int c = tid + (i << 8);
            const int row = c >> 3, col = (c & 7) << 2;
            uint4 u;
            if (A_F32) {
                u.x = packbf(__uint_as_float(rA[i].x));
                u.y = packbf(__uint_as_float(rA[i].y));
                u.z = packbf(__uint_as_float(rA[i].z));
                u.w = packbf(__uint_as_float(rA[i].w));
            } else {
                u = rA[i];
            }
            *(uint4*)&Asm[p][row * 36 + col] = u;
        }
    };
    bf16x8 bh[NT], bl[NT];
    auto ldB = [&](int t) {
        #pragma unroll
        for (int nt = 0; nt < NT; ++nt) {
            const int tg = (n0 >> 4) + wn * NT + nt;
            const size_t fb = ((size_t)(tg * nk + t) * 2) * 512 + lane * 8;
            bh[nt] = *(const bf16x8*)(Wf + fb);
            if (SPLIT) bl[nt] = *(const bf16x8*)(Wf + fb + 512);
        }
    };

    // prologue: stage tile 0; B(0) + A(1) fly across the barrier (no vmcnt drain)
    ldA(0);
    stA(0);
    ldB(0);
    ldA(1);
    asm volatile("s_waitcnt lgkmcnt(0)\ns_barrier" ::: "memory");

    #pragma unroll 1
    for (int t = 0; t < nk; ++t) {
        const int p = t & 1;
        bf16x8 ah[4], al[4];
        #pragma unroll
        for (int mt = 0; mt < 4; ++mt) {
            const int r = wm * 64 + mt * 16 + c16;
            const int b = r * 36 + q * 8;
            unpack8(*(const uint4*)&Asm[p][b], *(const uint4*)&Asm[p][b + 4], ah[mt], al[mt]);
        }
        #pragma unroll
        for (int nt = 0; nt < NT; ++nt)
            #pragma unroll
            for (int mt = 0; mt < 4; ++mt) {
                acc[mt][nt] = __builtin_amdgcn_mfma_f32_16x16x32_bf16(ah[mt], bh[nt], acc[mt][nt], 0, 0, 0);
                if (SPLIT) {
                    acc[mt][nt] = __builtin_amdgcn_mfma_f32_16x16x32_bf16(ah[mt], bl[nt], acc[mt][nt], 0, 0, 0);
                    acc[mt][nt] = __builtin_amdgcn_mfma_f32_16x16x32_bf16(al[mt], bh[nt], acc[mt][nt], 0, 0, 0);
                }
            }
        if (t + 1 < nk) {
            ldB(t + 1);              // WAR on bh: issued after MFMAs consumed it
            stA(p ^ 1);              // counted-vmcnt wait on rA(t+1), ~1 iter old
            if (t + 2 < nk) ldA((t + 2) << 5);   // refill rA; flies over barrier
            asm volatile("s_waitcnt lgkmcnt(0)\ns_barrier" ::: "memory");
        }
    }

    #pragma unroll
    for (int nt = 0; nt < NT; ++nt) {
        const int gcol = n0 + wn * (BN / 2) + nt * 16 + c16;
        const float bb = bias[gcol];
        #pragma unroll
        for (int mt = 0; mt < 4; ++mt)
            #pragma unroll
            for (int r = 0; r < 4; ++r) {
                const int grow = m0 + wm * 64 + mt * 16 + q * 4 + r;
                float v = acc[mt][nt][r] + bb;
                if (relu) v = fmaxf(v, 0.f);
                if (OUTP) ((unsigned*)Cp)[(size_t)grow * N + gcol] = packbf(v);
                else      ((float*)Cp)[(size_t)grow * N + gcol] = v;
            }
    }
}

// ---------------- VQ sweep v2: frag-layout codebook, 128 rows/block ------------
struct VqB2 {
    const unsigned* zep[10];
    const unsigned short* cbf[10];
    const float* cbn[10];
    int e_base[10];
};
__global__ __launch_bounds__(256) void vq_sweep2(
    VqB2 vb, float* __restrict__ bdo, int* __restrict__ bio)
{
    const int tid = threadIdx.x;
    const int lane = tid & 63, wv = tid >> 6;
    const int q = lane >> 4, c16 = lane & 15;
    const int chunk = blockIdx.y;
    const int s0 = blockIdx.x * 128 + wv * 32;
    const unsigned* zep = vb.zep[chunk];
    const int e_base = vb.e_base[chunk];
    const unsigned short* lbase =
        vb.cbf[chunk] + (size_t)(e_base >> 4) * 2048 + lane * 8;
    const float* cbn = vb.cbn[chunk] + e_base;

    bf16x8 ah[2][2], al[2][2];
    #pragma unroll
    for (int mt = 0; mt < 2; ++mt)
        #pragma unroll
        for (int ks = 0; ks < 2; ++ks) {
            const size_t a = (size_t)(s0 + mt * 16 + c16) * 64 + ks * 32 + q * 8;
            unpack8(*(const uint4*)(zep + a), *(const uint4*)(zep + a + 4),
                    ah[mt][ks], al[mt][ks]);
        }

    float bs[2][4];
    int   bi[2][4];
    #pragma unroll
    for (int mt = 0; mt < 2; ++mt)
        #pragma unroll
        for (int r = 0; r < 4; ++r) { bs[mt][r] = -3.4e38f; bi[mt][r] = 0x7fffffff; }

    auto ldT = [&](int t, bf16x8& b00, bf16x8& b01, bf16x8& b10, bf16x8& b11,
                   float& nn) {
        const unsigned short* p = lbase + (size_t)t * 2048;
        b00 = *(const bf16x8*)(p);
        b01 = *(const bf16x8*)(p + 512);
        b10 = *(const bf16x8*)(p + 1024);
        b11 = *(const bf16x8*)(p + 1536);
        nn = cbn[t * 16 + c16];
    };
    auto PROC = [&](const bf16x8& b00, const bf16x8& b01, const bf16x8& b10,
                    const bf16x8& b11, float nn, int t) {
        const float seed = -0.5f * nn;
        f32x4 a0 = {seed, seed, seed, seed};
        f32x4 a1 = a0;
        a0 = __builtin_amdgcn_mfma_f32_16x16x32_bf16(ah[0][0], b00, a0, 0, 0, 0);
        a1 = __builtin_amdgcn_mfma_f32_16x16x32_bf16(ah[1][0], b00, a1, 0, 0, 0);
        a0 = __builtin_amdgcn_mfma_f32_16x16x32_bf16(ah[0][0], b01, a0, 0, 0, 0);
        a1 = __builtin_amdgcn_mfma_f32_16x16x32_bf16(ah[1][0], b01, a1, 0, 0, 0);
        a0 = __builtin_amdgcn_mfma_f32_16x16x32_bf16(al[0][0], b00, a0, 0, 0, 0);
        a1 = __builtin_amdgcn_mfma_f32_16x16x32_bf16(al[1][0], b00, a1, 0, 0, 0);
        a0 = __builtin_amdgcn_mfma_f32_16x16x32_bf16(ah[0][1], b10, a0, 0, 0, 0);
        a1 = __builtin_amdgcn_mfma_f32_16x16x32_bf16(ah[1][1], b10, a1, 0, 0, 0);
        a0 = __builtin_amdgcn_mfma_f32_16x16x32_bf16(ah[0][1], b11, a0, 0, 0, 0);
        a1 = __builtin_amdgcn_mfma_f32_16x16x32_bf16(ah[1][1], b11, a1, 0, 0, 0);
        a0 = __builtin_amdgcn_mfma_f32_16x16x32_bf16(al[0][1], b10, a0, 0, 0, 0);
        a1 = __builtin_amdgcn_mfma_f32_16x16x32_bf16(al[1][1], b10, a1, 0, 0, 0);
        const int eidx = e_base + t * 16 + c16;
        #pragma unroll
        for (int r = 0; r < 4; ++r) {
            const float v0 = a0[r];
            if (v0 > bs[0][r]) { bs[0][r] = v0; bi[0][r] = eidx; }
            const float v1 = a1[r];
            if (v1 > bs[1][r]) { bs[1][r] = v1; bi[1][r] = eidx; }
        }
    };

    bf16x8 A00, A01, A10, A11, B00, B01, B10, B11;
    float nA, nB;
    ldT(0, A00, A01, A10, A11, nA);
    #pragma unroll 1
    for (int t = 0; t < 64; t += 2) {
        ldT(t + 1, B00, B01, B10, B11, nB);
        PROC(A00, A01, A10, A11, nA, t);
        if (t + 2 < 64) ldT(t + 2, A00, A01, A10, A11, nA);
        PROC(B00, B01, B10, B11, nB, t + 1);
    }

    #pragma unroll
    for (int off = 1; off < 16; off <<= 1)
        #pragma unroll
        for (int mt = 0; mt < 2; ++mt)
            #pragma unroll
            for (int r = 0; r < 4; ++r) {
                const float od = __shfl_xor(bs[mt][r], off, 64);
                const int   oi = __shfl_xor(bi[mt][r], off, 64);
                if (od > bs[mt][r] || (od == bs[mt][r] && oi < bi[mt][r])) {
                    bs[mt][r] = od; bi[mt][r] = oi;
                }
            }
    if (c16 == 0) {
        #pragma unroll
        for (int mt = 0; mt < 2; ++mt)
            #pragma unroll
            for (int r = 0; r < 4; ++r) {
                const int row = s0 + mt * 16 + q * 4 + r;
                bdo[(size_t)chunk * BSZ + row] = -2.0f * bs[mt][r];
                bio[(size_t)chunk * BSZ + row] = bi[mt][r];
            }
    }
}

// ---------------- merge chunks + gather zq planes (all 3 levels) ----------------
__global__ __launch_bounds__(256) void merge_gather_b(
    const float* __restrict__ bd, const int* __restrict__ bi,
    const unsigned* __restrict__ cb0, const unsigned* __restrict__ cb1,
    const unsigned* __restrict__ cb2, unsigned* __restrict__ zq_all)
{
    const int gid = blockIdx.x * 256 + threadIdx.x;   // 0 .. 3*BSZ*64
    const int l = gid / (BSZ * 64);
    const int r = gid - l * (BSZ * 64);
    const int s = r >> 6, d = r & 63;
    const int c0 = (l == 0) ? 0 : (l == 1 ? 2 : 6);
    const int c1 = (l == 0) ? 2 : (l == 1 ? 6 : 10);
    float best = bd[(size_t)c0 * BSZ + s];
    int   idx  = bi[(size_t)c0 * BSZ + s];
    for (int c = c0 + 1; c < c1; ++c) {
        const float dd = bd[(size_t)c * BSZ + s];
        const int   ii = bi[(size_t)c * BSZ + s];
        if (dd < best || (dd == best && ii < idx)) { best = dd; idx = ii; }
    }
    const unsigned* cb = (l == 0) ? cb0 : (l == 1 ? cb1 : cb2);
    zq_all[gid] = cb[(size_t)idx * 64 + d];
}

// ---------------- batched losses ----------------
__global__ __launch_bounds__(256) void loss_b(
    const unsigned* __restrict__ zep0, const unsigned* __restrict__ zq0,
    const unsigned* __restrict__ attb, float* __restrict__ vq_out,
    float* __restrict__ commit_out, float inv)
{
    const int l = blockIdx.z;
    const unsigned* ze = zep0 + (size_t)l * BSZ * 64;
    const unsigned* zq = zq0 + (size_t)l * BSZ * 64;
    const unsigned* at = (l > 0) ? attb + (size_t)(l - 1) * BSZ * 64 : nullptr;
    float cs = 0.f, vs = 0.f;
    for (int t = blockIdx.x * 256 + threadIdx.x; t < BSZ * 64; t += gridDim.x * 256) {
        const float e = unpackf(ze[t]);
        const float qv = unpackf(zq[t]);
        const float dc = e - qv;
        cs += dc * dc;
        const float za = at ? (e + unpackf(at[t])) : e;
        const float dv = qv - za;
        vs += dv * dv;
    }
    #pragma unroll
    for (int off = 32; off; off >>= 1) {
        cs += __shfl_down(cs, off, 64);
        vs += __shfl_down(vs, off, 64);
    }
    __shared__ float sc[4], sv[4];
    const int lane = threadIdx.x & 63, w = threadIdx.x >> 6;
    if (lane == 0) { sc[w] = cs; sv[w] = vs; }
    __syncthreads();
    if (threadIdx.x == 0) {
        atomicAdd(commit_out, (sc[0] + sc[1] + sc[2] + sc[3]) * inv);
        atomicAdd(vq_out, (sv[0] + sv[1] + sv[2] + sv[3]) * inv);
    }
}

extern "C" void kernel_launch(void* const* d_in, const int* in_sizes, int n_in,
                              void* d_out, int out_size, void* d_ws, size_t ws_size,
                              hipStream_t stream)
{
    const int CB_SIZES[3] = {2048, 4096, 4096};

    // ---- workspace layout (u32 units) ----
    unsigned* H1   = (unsigned*)d_ws;                  // 3 * B*256
    unsigned* H2   = H1 + (size_t)3 * BSZ * 256;       // 3 * B*256
    unsigned* ZEP  = H2 + (size_t)3 * BSZ * 256;       // 3 * B*64
    unsigned* ZQ   = ZEP + (size_t)3 * BSZ * 64;       // 3 * B*64
    unsigned* ATT  = ZQ + (size_t)3 * BSZ * 64;        // 2 * B*64
    float* cbn     = (float*)(ATT + (size_t)2 * BSZ * 64);  // 10240
    float* bd      = cbn + 10240;                      // 10 * BSZ
    int*   bi      = (int*)(bd + 10 * BSZ);            // 10 * BSZ
    unsigned* wcb  = (unsigned*)(bi + 10 * BSZ);       // 2*4096 fragged wcomb
    float* bcomb   = (float*)(wcb + 2 * 4096);         // 2*64
    unsigned* wp   = (unsigned*)(bcomb + 128);         // codebook interleaved planes

    float* out = (float*)d_out;
    float* vq_loss = out + (size_t)3 * BSZ * 512;
    float* commit  = vq_loss + 1;
    hipMemsetAsync(vq_loss, 0, 2 * sizeof(float), stream);

    // ---- prep: codebooks only -> interleaved planes (for merge_gather) ----
    PrepArgs pa; int pos = 0, ns = 0;
    const unsigned* cbp[3];
    auto add = [&](const float* src, int n) -> const unsigned* {
        pa.src[ns] = src; pa.dst[ns] = wp + pos; pa.start[ns] = pos;
        pos += n; ns++; return wp + pos - n;
    };
    for (int l = 0; l < 3; ++l)
        cbp[l] = add((const float*)d_in[3 + 13 * l + 12], CB_SIZES[l] * 64);
    pa.start[ns] = pos; pa.nseg = ns;
    for (int i = ns + 1; i < 24; ++i) pa.start[i] = 0x7fffffff;

    // fragged codebooks after wp
    unsigned short* cbf0 = (unsigned short*)(wp + pos);
    unsigned short* cbf1 = cbf0 + (size_t)2048 * 128;
    unsigned short* cbf2 = cbf1 + (size_t)4096 * 128;
    // fragged weights after codebook frags (10240*128 ushorts total above)
    unsigned short* wfr = (unsigned short*)(wp + pos + 655360);

    // ---- w_frag descriptor (slots = N*K/4: BOTH planes!) ----
    WFragArgs wa; int fpos = 0, wslot = 0;
    const unsigned short* wfp[3][6];
    auto addw = [&](const float* src, int Nn, int Kk, int kl) -> const unsigned short* {
        wa.src[wslot] = src; wa.dst[wslot] = wfr + (size_t)fpos * 8;
        wa.start[wslot] = fpos; wa.kslog[wslot] = kl;
        fpos += Nn * Kk / 4; wslot++;
        return wa.dst[wslot - 1];
    };
    for (int l = 0; l < 3; ++l) {
        const int base = 3 + 13 * l;
        wfp[l][0] = addw((const float*)d_in[base + 0], 256, 512, 4);
        wfp[l][1] = addw((const float*)d_in[base + 2], 256, 256, 3);
        wfp[l][2] = addw((const float*)d_in[base + 4], 64, 256, 3);
        wfp[l][3] = addw((const float*)d_in[base + 6], 256, 64, 1);
        wfp[l][4] = addw((const float*)d_in[base + 8], 256, 256, 3);
        wfp[l][5] = addw((const float*)d_in[base + 10], 512, 256, 3);
    }
    wa.start[18] = fpos;   // 319488

    hipLaunchKernelGGL(prep_kernel, dim3(pos >> 10), dim3(256), 0, stream, pa);
    hipLaunchKernelGGL(cb_norms3, dim3(40), dim3(256), 0, stream,
                       (const float*)d_in[15], (const float*)d_in[28], (const float*)d_in[41], cbn);
    hipLaunchKernelGGL(cb_frag3, dim3(640), dim3(256), 0, stream,
                       (const float*)d_in[15], (const float*)d_in[28], (const float*)d_in[41],
                       cbf0, cbf1, cbf2);
    hipLaunchKernelGGL(w_frag, dim3(fpos / 256), dim3(256), 0, stream, wa);
    for (int j = 0; j < 2; ++j)
        hipLaunchKernelGGL(attn_combine, dim3(1), dim3(256), 0, stream,
                           (const float*)d_in[42 + 4 * j], (const float*)d_in[42 + 4 * j + 1],
                           (const float*)d_in[42 + 4 * j + 2], (const float*)d_in[42 + 4 * j + 3],
                           wcb + j * 4096, bcomb + j * 64);

    // ---- encoders, batched over levels (split-bf16, fp32-grade) ----
    GemmB g;
    for (int l = 0; l < 3; ++l) {
        g.A[l] = d_in[l]; g.W[l] = wfp[l][0];
        g.bias[l] = (const float*)d_in[3 + 13 * l + 1];
        g.C[l] = H1 + (size_t)l * BSZ * 256;
    }
    hipLaunchKernelGGL((gemmb5<1, 128, 1, 1>), dim3(2, 128, 3), dim3(256), 0, stream,
                       g, BSZ, 256, 512, 1);
    for (int l = 0; l < 3; ++l) {
        g.A[l] = H1 + (size_t)l * BSZ * 256; g.W[l] = wfp[l][1];
        g.bias[l] = (const float*)d_in[3 + 13 * l + 3];
        g.C[l] = H2 + (size_t)l * BSZ * 256;
    }
    hipLaunchKernelGGL((gemmb5<1, 128, 0, 1>), dim3(2, 128, 3), dim3(256), 0, stream,
                       g, BSZ, 256, 256, 1);
    for (int l = 0; l < 3; ++l) {
        g.A[l] = H2 + (size_t)l * BSZ * 256; g.W[l] = wfp[l][2];
        g.bias[l] = (const float*)d_in[3 + 13 * l + 5];
        g.C[l] = ZEP + (size_t)l * BSZ * 64;
    }
    hipLaunchKernelGGL((gemmb5<1, 64, 0, 1>), dim3(1, 128, 3), dim3(256), 0, stream,
                       g, BSZ, 64, 256, 0);

    // ---- VQ: 10 chunks of 1024 entries (l0:2, l1:4, l2:4) ----
    VqB2 vb;
    {
        const unsigned short* cbfl[3] = {cbf0, cbf1, cbf2};
        int c = 0;
        for (int l = 0; l < 3; ++l) {
            const int nch = CB_SIZES[l] / 1024;
            const int cb_off = (l == 0) ? 0 : (l == 1 ? 2048 : 6144);
            for (int k = 0; k < nch; ++k, ++c) {
                vb.zep[c] = ZEP + (size_t)l * BSZ * 64;
                vb.cbf[c] = cbfl[l];
                vb.cbn[c] = cbn + cb_off;
                vb.e_base[c] = k * 1024;
            }
        }
    }
    hipLaunchKernelGGL(vq_sweep2, dim3(BSZ / 128, 10), dim3(256), 0, stream, vb, bd, bi);
    hipLaunchKernelGGL(merge_gather_b, dim3(3 * BSZ * 64 / 256), dim3(256), 0, stream,
                       bd, bi, cbp[0], cbp[1], cbp[2], ZQ);

    // ---- folded attention (loss-only), batched over 2 ----
    for (int j = 0; j < 2; ++j) {
        g.A[j] = ZQ + (size_t)j * BSZ * 64;
        g.W[j] = (const unsigned short*)(wcb + j * 4096);
        g.bias[j] = bcomb + j * 64;
        g.C[j] = ATT + (size_t)j * BSZ * 64;
    }
    g.A[2] = g.A[1]; g.W[2] = g.W[1]; g.bias[2] = g.bias[1]; g.C[2] = g.C[1];
    hipLaunchKernelGGL((gemmb5<0, 64, 0, 1>), dim3(1, 128, 2), dim3(256), 0, stream,
                       g, BSZ, 64, 64, 0);

    // ---- losses, batched over 3 ----
    hipLaunchKernelGGL(loss_b, dim3(256, 1, 3), dim3(256), 0, stream,
                       ZEP, ZQ, ATT, vq_loss, commit, 1.0f / (float)(BSZ * 64));

    // ---- decoders, batched over levels (plain bf16) ----
    for (int l = 0; l < 3; ++l) {
        g.A[l] = ZQ + (size_t)l * BSZ * 64; g.W[l] = wfp[l][3];
        g.bias[l] = (const float*)d_in[3 + 13 * l + 7];
        g.C[l] = H1 + (size_t)l * BSZ * 256;
    }
    hipLaunchKernelGGL((gemmb5<0, 128, 0, 1>), dim3(2, 128, 3), dim3(256), 0, stream,
                       g, BSZ, 256, 64, 1);
    for (int l = 0; l < 3; ++l) {
        g.A[l] = H1 + (size_t)l * BSZ * 256; g.W[l] = wfp[l][4];
        g.bias[l] = (const float*)d_in[3 + 13 * l + 9];
        g.C[l] = H2 + (size_t)l * BSZ * 256;
    }
    hipLaunchKernelGGL((gemmb5<0, 128, 0, 1>), dim3(2, 128, 3), dim3(256), 0, stream,
                       g, BSZ, 256, 256, 1);
    for (int l = 0; l < 3; ++l) {
        g.A[l] = H2 + (size_t)l * BSZ * 256; g.W[l] = wfp[l][5];
        g.bias[l] = (const float*)d_in[3 + 13 * l + 11];
        g.C[l] = out + (size_t)l * BSZ * 512;
    }
    hipLaunchKernelGGL((gemmb5<0, 128, 0, 0>), dim3(4, 128, 3), dim3(256), 0, stream,
                       g, BSZ, 512, 256, 0);
}

// Round 8
// 560.655 us; speedup vs baseline: 1.0559x; 1.0559x over previous
//
#include <hip/hip_runtime.h>

#define BSZ 16384

typedef __attribute__((ext_vector_type(8))) short bf16x8;
typedef __attribute__((ext_vector_type(4))) float f32x4;
typedef __attribute__((ext_vector_type(8))) unsigned short u16x8;

// pack fp32 -> interleaved (hi bf16 | lo bf16 << 16); hi+lo ~= x within 2^-16 rel
__device__ inline unsigned packbf(float v) {
    unsigned u = __float_as_uint(v);
    unsigned r = u + (0x7fffu + ((u >> 16) & 1u));
    unsigned hi = r >> 16;
    float rem = v - __uint_as_float(r & 0xffff0000u);
    unsigned lu = __float_as_uint(rem);
    unsigned lo = (lu + (0x7fffu + ((lu >> 16) & 1u))) >> 16;
    return hi | (lo << 16);
}
__device__ inline float unpackf(unsigned u) {
    return __uint_as_float(u << 16) + __uint_as_float(u & 0xffff0000u);
}
// 8 interleaved elems (two uint4) -> hi-plane and lo-plane bf16x8 frags
__device__ inline void unpack8(const uint4 p0, const uint4 p1, bf16x8& hi, bf16x8& lo) {
    union { unsigned u[4]; bf16x8 v; } H, L;
    H.u[0] = __builtin_amdgcn_perm(p0.y, p0.x, 0x05040100u);
    H.u[1] = __builtin_amdgcn_perm(p0.w, p0.z, 0x05040100u);
    H.u[2] = __builtin_amdgcn_perm(p1.y, p1.x, 0x05040100u);
    H.u[3] = __builtin_amdgcn_perm(p1.w, p1.z, 0x05040100u);
    L.u[0] = __builtin_amdgcn_perm(p0.y, p0.x, 0x07060302u);
    L.u[1] = __builtin_amdgcn_perm(p0.w, p0.z, 0x07060302u);
    L.u[2] = __builtin_amdgcn_perm(p1.y, p1.x, 0x07060302u);
    L.u[3] = __builtin_amdgcn_perm(p1.w, p1.z, 0x07060302u);
    hi = H.v; lo = L.v;
}

// ---------------- prep: fp32 -> interleaved planes (codebooks only now) --------
struct PrepArgs {
    const float* src[24];
    unsigned* dst[24];
    int start[24];   // prefix (elements); all sizes multiples of 1024
    int nseg;
};
__global__ __launch_bounds__(256) void prep_kernel(PrepArgs pa) {
    const int base = blockIdx.x << 10;
    int seg = 0;
    #pragma unroll 1
    for (int i = 0; i < 23; ++i)
        if (seg + 1 < pa.nseg && base >= pa.start[seg + 1]) seg++;
    const int off = base - pa.start[seg] + (threadIdx.x << 2);
    const float4 v = *(const float4*)(pa.src[seg] + off);
    uint4 u;
    u.x = packbf(v.x); u.y = packbf(v.y); u.z = packbf(v.z); u.w = packbf(v.w);
    *(uint4*)(pa.dst[seg] + off) = u;
}

// ---------------- codebook norms (all 3 levels, fp32 inputs) ----------------
__global__ __launch_bounds__(256) void cb_norms3(
    const float* __restrict__ c0, const float* __restrict__ c1,
    const float* __restrict__ c2, float* __restrict__ cbn)
{
    const int r = blockIdx.x * 256 + threadIdx.x;   // 0..10239
    const float* src; int off;
    if (r < 2048) { src = c0; off = r; }
    else if (r < 6144) { src = c1; off = r - 2048; }
    else { src = c2; off = r - 6144; }
    const float4* p = (const float4*)(src + (size_t)off * 64);
    float s = 0.f;
    #pragma unroll
    for (int c = 0; c < 16; ++c) {
        float4 v = p[c];
        s += v.x * v.x + v.y * v.y + v.z * v.z + v.w * v.w;
    }
    cbn[r] = s;
}

// ---------------- codebook -> MFMA-fragment-ordered split bf16 planes ----------
__global__ __launch_bounds__(256) void cb_frag3(
    const float* __restrict__ c0, const float* __restrict__ c1,
    const float* __restrict__ c2, unsigned short* __restrict__ f0,
    unsigned short* __restrict__ f1, unsigned short* __restrict__ f2)
{
    int g = blockIdx.x * 256 + threadIdx.x;   // 0 .. 10240*16
    const float* src; unsigned short* dst;
    if (g < 32768) { src = c0; dst = f0; }
    else if (g < 98304) { src = c1; dst = f1; g -= 32768; }
    else { src = c2; dst = f2; g -= 98304; }
    const int l = g & 63;
    const int fr = g >> 6;
    const int t = fr >> 2, ks = (fr >> 1) & 1, pln = fr & 1;
    const int e = t * 16 + (l & 15);
    const int d0 = ks * 32 + (l >> 4) * 8;
    const float* s = src + (size_t)e * 64 + d0;
    union { unsigned short o[8]; u16x8 v; } U;
    #pragma unroll
    for (int j = 0; j < 8; ++j) {
        const float v = s[j];
        const unsigned u = __float_as_uint(v);
        const unsigned r = u + (0x7fffu + ((u >> 16) & 1u));
        if (pln == 0) {
            U.o[j] = (unsigned short)(r >> 16);
        } else {
            const float rem = v - __uint_as_float(r & 0xffff0000u);
            const unsigned lu = __float_as_uint(rem);
            U.o[j] = (unsigned short)((lu + (0x7fffu + ((lu >> 16) & 1u))) >> 16);
        }
    }
    *(u16x8*)(dst + (size_t)g * 8) = U.v;
}

// ---------------- weights -> MFMA-fragment-ordered split bf16 planes ----------
// frame f = (nt*(K/32)+ks)*2+p, lane l holds entry n = nt*16+(l&15),
// dims d0 = ks*32+(l>>4)*8.  Slots per segment = N*K/4 (TWO planes).
struct WFragArgs {
    const float* src[18];
    unsigned short* dst[18];
    int start[19];   // prefix in lane-slots (elems*2/8)
    int kslog[18];   // log2(K/32)
};
__global__ __launch_bounds__(256) void w_frag(WFragArgs wa) {
    const int gid = blockIdx.x * 256 + threadIdx.x;
    int seg = 0;
    #pragma unroll 1
    for (int i = 0; i < 17; ++i)
        if (gid >= wa.start[seg + 1]) seg++;
    const int s = gid - wa.start[seg];
    const int l = s & 63, fr = s >> 6;
    const int kl = wa.kslog[seg];
    const int pln = fr & 1;
    const int ks = (fr >> 1) & ((1 << kl) - 1);
    const int nt = fr >> (1 + kl);
    const int K = 32 << kl;
    const int n = nt * 16 + (l & 15);
    const int d0 = ks * 32 + (l >> 4) * 8;
    const float* sp = wa.src[seg] + (size_t)n * K + d0;
    union { unsigned short o[8]; u16x8 v; } U;
    #pragma unroll
    for (int j = 0; j < 8; ++j) {
        const float v = sp[j];
        const unsigned u = __float_as_uint(v);
        const unsigned r = u + (0x7fffu + ((u >> 16) & 1u));
        if (pln == 0) {
            U.o[j] = (unsigned short)(r >> 16);
        } else {
            const float rem = v - __uint_as_float(r & 0xffff0000u);
            const unsigned lu = __float_as_uint(rem);
            U.o[j] = (unsigned short)((lu + (0x7fffu + ((lu >> 16) & 1u))) >> 16);
        }
    }
    *(u16x8*)(wa.dst[seg] + (size_t)s * 8) = U.v;
}

// ---------------- attention fold: W_comb = ow@wv (FRAGGED planes) ----------------
__global__ __launch_bounds__(256) void attn_combine(
    const float* __restrict__ iw, const float* __restrict__ ib,
    const float* __restrict__ ow, const float* __restrict__ ob,
    unsigned* __restrict__ wcomb, float* __restrict__ bcomb)
{
    __shared__ float o[4096], v[4096];
    const float* wv = iw + 128 * 64;
    for (int t = threadIdx.x; t < 4096; t += 256) { o[t] = ow[t]; v[t] = wv[t]; }
    __syncthreads();
    unsigned short* wc = (unsigned short*)wcomb;
    for (int t = threadIdx.x; t < 4096; t += 256) {
        const int j = t >> 6, i = t & 63;   // j = out dim (n), i = in dim (k)
        float s = 0.f;
        #pragma unroll
        for (int k = 0; k < 64; ++k) s += o[j * 64 + k] * v[k * 64 + i];
        const unsigned u = __float_as_uint(s);
        const unsigned r = u + (0x7fffu + ((u >> 16) & 1u));
        const unsigned short hi = (unsigned short)(r >> 16);
        const float rem = s - __uint_as_float(r & 0xffff0000u);
        const unsigned lu = __float_as_uint(rem);
        const unsigned short lo = (unsigned short)((lu + (0x7fffu + ((lu >> 16) & 1u))) >> 16);
        const int nt = j >> 4, ks = i >> 5;
        const int lsub = (j & 15) | (((i >> 3) & 3) << 4);
        const int e = i & 7;
        wc[(size_t)((nt * 2 + ks) * 2 + 0) * 512 + lsub * 8 + e] = hi;
        wc[(size_t)((nt * 2 + ks) * 2 + 1) * 512 + lsub * 8 + e] = lo;
    }
    if (threadIdx.x < 64) {
        const int j = threadIdx.x;
        const float* bv = ib + 128;
        float s = ob[j];
        #pragma unroll
        for (int k = 0; k < 64; ++k) s += o[j * 64 + k] * bv[k];
        bcomb[j] = s;
    }
}

// ---------------- batched MFMA GEMM v6: gemmb4 structure, BM=64 tile ----------
// Same proven data path as gemmb4 (round 6, 578.6us): interleaved stride-36
// A-LDS, two __syncthreads per K-step, unpack8 frag reads, fragged-W direct B,
// identical per-output MFMA accumulation order. Only change: BM 128->64, which
// doubles the grid (6 blocks/CU vs 3) and halves LDS (9.2KB) to lift the
// 15%-occupancy starvation seen in r6/r7 counters.
struct GemmB {
    const void* A[3];
    const unsigned short* W[3];
    const float* bias[3];
    void* C[3];
};
template<int SPLIT, int BN, int A_F32, int OUTP>
__global__ __launch_bounds__(256) void gemmb6(
    GemmB g, int M, int N, int K, int relu)
{
    constexpr int NT = BN / 32;
    __shared__ unsigned Asm[64 * 36];
    const int z = blockIdx.z;
    const void* Ap_ = g.A[z];
    const unsigned short* Wf = g.W[z];
    const float* bias = g.bias[z];
    void* Cp = g.C[z];
    const int tid = threadIdx.x;
    const int m0 = blockIdx.y << 6;
    const int n0 = blockIdx.x * BN;
    const int lane = tid & 63, wv = tid >> 6;
    const int wm = wv >> 1, wn = wv & 1;
    const int q = lane >> 4, c16 = lane & 15;
    const int nk = K >> 5;

    f32x4 acc[2][NT] = {};

    uint4 rA[2];
    auto ldA = [&](int k0) {
        #pragma unroll
        for (int i = 0; i < 2; ++i) {
            const int c = tid + (i << 8);
            const int row = c >> 3, col = (c & 7) << 2;
            rA[i] = *(const uint4*)((const unsigned*)Ap_ + (size_t)(m0 + row) * K + k0 + col);
        }
    };
    bf16x8 bh[NT], bl[NT];
    auto ldB = [&](int t) {
        #pragma unroll
        for (int nt = 0; nt < NT; ++nt) {
            const int tg = (n0 >> 4) + wn * NT + nt;
            const size_t fb = ((size_t)(tg * nk + t) * 2) * 512 + lane * 8;
            bh[nt] = *(const bf16x8*)(Wf + fb);
            if (SPLIT) bl[nt] = *(const bf16x8*)(Wf + fb + 512);
        }
    };

    ldA(0);
    ldB(0);

    #pragma unroll 1
    for (int t = 0; t < nk; ++t) {
        __syncthreads();   // Asm readers of tile t-1 are done
        #pragma unroll
        for (int i = 0; i < 2; ++i) {
            const int c = tid + (i << 8);
            const int row = c >> 3, col = (c & 7) << 2;
            uint4 u;
            if (A_F32) {
                u.x = packbf(__uint_as_float(rA[i].x));
                u.y = packbf(__uint_as_float(rA[i].y));
                u.z = packbf(__uint_as_float(rA[i].z));
                u.w = packbf(__uint_as_float(rA[i].w));
            } else {
                u = rA[i];
            }
            *(uint4*)&Asm[row * 36 + col] = u;
        }
        if (t + 1 < nk) ldA((t + 1) << 5);   // prefetch
        __syncthreads();

        bf16x8 ah[2], al[2];
        #pragma unroll
        for (int mt = 0; mt < 2; ++mt) {
            const int r = wm * 32 + mt * 16 + c16;
            const int b = r * 36 + q * 8;
            unpack8(*(const uint4*)&Asm[b], *(const uint4*)&Asm[b + 4], ah[mt], al[mt]);
        }
        #pragma unroll
        for (int nt = 0; nt < NT; ++nt)
            #pragma unroll
            for (int mt = 0; mt < 2; ++mt) {
                acc[mt][nt] = __builtin_amdgcn_mfma_f32_16x16x32_bf16(ah[mt], bh[nt], acc[mt][nt], 0, 0, 0);
                if (SPLIT) {
                    acc[mt][nt] = __builtin_amdgcn_mfma_f32_16x16x32_bf16(ah[mt], bl[nt], acc[mt][nt], 0, 0, 0);
                    acc[mt][nt] = __builtin_amdgcn_mfma_f32_16x16x32_bf16(al[mt], bh[nt], acc[mt][nt], 0, 0, 0);
                }
            }
        if (t + 1 < nk) ldB(t + 1);   // L2 latency covered by next stage phase
    }

    #pragma unroll
    for (int nt = 0; nt < NT; ++nt) {
        const int gcol = n0 + wn * (BN / 2) + nt * 16 + c16;
        const float bb = bias[gcol];
        #pragma unroll
        for (int mt = 0; mt < 2; ++mt)
            #pragma unroll
            for (int r = 0; r < 4; ++r) {
                const int grow = m0 + wm * 32 + mt * 16 + q * 4 + r;
                float v = acc[mt][nt][r] + bb;
                if (relu) v = fmaxf(v, 0.f);
                if (OUTP) ((unsigned*)Cp)[(size_t)grow * N + gcol] = packbf(v);
                else      ((float*)Cp)[(size_t)grow * N + gcol] = v;
            }
    }
}

// ---------------- VQ sweep v2: frag-layout codebook, 128 rows/block ------------
struct VqB2 {
    const unsigned* zep[10];
    const unsigned short* cbf[10];
    const float* cbn[10];
    int e_base[10];
};
__global__ __launch_bounds__(256) void vq_sweep2(
    VqB2 vb, float* __restrict__ bdo, int* __restrict__ bio)
{
    const int tid = threadIdx.x;
    const int lane = tid & 63, wv = tid >> 6;
    const int q = lane >> 4, c16 = lane & 15;
    const int chunk = blockIdx.y;
    const int s0 = blockIdx.x * 128 + wv * 32;
    const unsigned* zep = vb.zep[chunk];
    const int e_base = vb.e_base[chunk];
    const unsigned short* lbase =
        vb.cbf[chunk] + (size_t)(e_base >> 4) * 2048 + lane * 8;
    const float* cbn = vb.cbn[chunk] + e_base;

    bf16x8 ah[2][2], al[2][2];
    #pragma unroll
    for (int mt = 0; mt < 2; ++mt)
        #pragma unroll
        for (int ks = 0; ks < 2; ++ks) {
            const size_t a = (size_t)(s0 + mt * 16 + c16) * 64 + ks * 32 + q * 8;
            unpack8(*(const uint4*)(zep + a), *(const uint4*)(zep + a + 4),
                    ah[mt][ks], al[mt][ks]);
        }

    float bs[2][4];
    int   bi[2][4];
    #pragma unroll
    for (int mt = 0; mt < 2; ++mt)
        #pragma unroll
        for (int r = 0; r < 4; ++r) { bs[mt][r] = -3.4e38f; bi[mt][r] = 0x7fffffff; }

    auto ldT = [&](int t, bf16x8& b00, bf16x8& b01, bf16x8& b10, bf16x8& b11,
                   float& nn) {
        const unsigned short* p = lbase + (size_t)t * 2048;
        b00 = *(const bf16x8*)(p);
        b01 = *(const bf16x8*)(p + 512);
        b10 = *(const bf16x8*)(p + 1024);
        b11 = *(const bf16x8*)(p + 1536);
        nn = cbn[t * 16 + c16];
    };
    auto PROC = [&](const bf16x8& b00, const bf16x8& b01, const bf16x8& b10,
                    const bf16x8& b11, float nn, int t) {
        const float seed = -0.5f * nn;
        f32x4 a0 = {seed, seed, seed, seed};
        f32x4 a1 = a0;
        a0 = __builtin_amdgcn_mfma_f32_16x16x32_bf16(ah[0][0], b00, a0, 0, 0, 0);
        a1 = __builtin_amdgcn_mfma_f32_16x16x32_bf16(ah[1][0], b00, a1, 0, 0, 0);
        a0 = __builtin_amdgcn_mfma_f32_16x16x32_bf16(ah[0][0], b01, a0, 0, 0, 0);
        a1 = __builtin_amdgcn_mfma_f32_16x16x32_bf16(ah[1][0], b01, a1, 0, 0, 0);
        a0 = __builtin_amdgcn_mfma_f32_16x16x32_bf16(al[0][0], b00, a0, 0, 0, 0);
        a1 = __builtin_amdgcn_mfma_f32_16x16x32_bf16(al[1][0], b00, a1, 0, 0, 0);
        a0 = __builtin_amdgcn_mfma_f32_16x16x32_bf16(ah[0][1], b10, a0, 0, 0, 0);
        a1 = __builtin_amdgcn_mfma_f32_16x16x32_bf16(ah[1][1], b10, a1, 0, 0, 0);
        a0 = __builtin_amdgcn_mfma_f32_16x16x32_bf16(ah[0][1], b11, a0, 0, 0, 0);
        a1 = __builtin_amdgcn_mfma_f32_16x16x32_bf16(ah[1][1], b11, a1, 0, 0, 0);
        a0 = __builtin_amdgcn_mfma_f32_16x16x32_bf16(al[0][1], b10, a0, 0, 0, 0);
        a1 = __builtin_amdgcn_mfma_f32_16x16x32_bf16(al[1][1], b10, a1, 0, 0, 0);
        const int eidx = e_base + t * 16 + c16;
        #pragma unroll
        for (int r = 0; r < 4; ++r) {
            const float v0 = a0[r];
            if (v0 > bs[0][r]) { bs[0][r] = v0; bi[0][r] = eidx; }
            const float v1 = a1[r];
            if (v1 > bs[1][r]) { bs[1][r] = v1; bi[1][r] = eidx; }
        }
    };

    bf16x8 A00, A01, A10, A11, B00, B01, B10, B11;
    float nA, nB;
    ldT(0, A00, A01, A10, A11, nA);
    #pragma unroll 1
    for (int t = 0; t < 64; t += 2) {
        ldT(t + 1, B00, B01, B10, B11, nB);
        PROC(A00, A01, A10, A11, nA, t);
        if (t + 2 < 64) ldT(t + 2, A00, A01, A10, A11, nA);
        PROC(B00, B01, B10, B11, nB, t + 1);
    }

    #pragma unroll
    for (int off = 1; off < 16; off <<= 1)
        #pragma unroll
        for (int mt = 0; mt < 2; ++mt)
            #pragma unroll
            for (int r = 0; r < 4; ++r) {
                const float od = __shfl_xor(bs[mt][r], off, 64);
                const int   oi = __shfl_xor(bi[mt][r], off, 64);
                if (od > bs[mt][r] || (od == bs[mt][r] && oi < bi[mt][r])) {
                    bs[mt][r] = od; bi[mt][r] = oi;
                }
            }
    if (c16 == 0) {
        #pragma unroll
        for (int mt = 0; mt < 2; ++mt)
            #pragma unroll
            for (int r = 0; r < 4; ++r) {
                const int row = s0 + mt * 16 + q * 4 + r;
                bdo[(size_t)chunk * BSZ + row] = -2.0f * bs[mt][r];
                bio[(size_t)chunk * BSZ + row] = bi[mt][r];
            }
    }
}

// ---------------- merge chunks + gather zq planes (all 3 levels) ----------------
__global__ __launch_bounds__(256) void merge_gather_b(
    const float* __restrict__ bd, const int* __restrict__ bi,
    const unsigned* __restrict__ cb0, const unsigned* __restrict__ cb1,
    const unsigned* __restrict__ cb2, unsigned* __restrict__ zq_all)
{
    const int gid = blockIdx.x * 256 + threadIdx.x;   // 0 .. 3*BSZ*64
    const int l = gid / (BSZ * 64);
    const int r = gid - l * (BSZ * 64);
    const int s = r >> 6, d = r & 63;
    const int c0 = (l == 0) ? 0 : (l == 1 ? 2 : 6);
    const int c1 = (l == 0) ? 2 : (l == 1 ? 6 : 10);
    float best = bd[(size_t)c0 * BSZ + s];
    int   idx  = bi[(size_t)c0 * BSZ + s];
    for (int c = c0 + 1; c < c1; ++c) {
        const float dd = bd[(size_t)c * BSZ + s];
        const int   ii = bi[(size_t)c * BSZ + s];
        if (dd < best || (dd == best && ii < idx)) { best = dd; idx = ii; }
    }
    const unsigned* cb = (l == 0) ? cb0 : (l == 1 ? cb1 : cb2);
    zq_all[gid] = cb[(size_t)idx * 64 + d];
}

// ---------------- batched losses ----------------
__global__ __launch_bounds__(256) void loss_b(
    const unsigned* __restrict__ zep0, const unsigned* __restrict__ zq0,
    const unsigned* __restrict__ attb, float* __restrict__ vq_out,
    float* __restrict__ commit_out, float inv)
{
    const int l = blockIdx.z;
    const unsigned* ze = zep0 + (size_t)l * BSZ * 64;
    const unsigned* zq = zq0 + (size_t)l * BSZ * 64;
    const unsigned* at = (l > 0) ? attb + (size_t)(l - 1) * BSZ * 64 : nullptr;
    float cs = 0.f, vs = 0.f;
    for (int t = blockIdx.x * 256 + threadIdx.x; t < BSZ * 64; t += gridDim.x * 256) {
        const float e = unpackf(ze[t]);
        const float qv = unpackf(zq[t]);
        const float dc = e - qv;
        cs += dc * dc;
        const float za = at ? (e + unpackf(at[t])) : e;
        const float dv = qv - za;
        vs += dv * dv;
    }
    #pragma unroll
    for (int off = 32; off; off >>= 1) {
        cs += __shfl_down(cs, off, 64);
        vs += __shfl_down(vs, off, 64);
    }
    __shared__ float sc[4], sv[4];
    const int lane = threadIdx.x & 63, w = threadIdx.x >> 6;
    if (lane == 0) { sc[w] = cs; sv[w] = vs; }
    __syncthreads();
    if (threadIdx.x == 0) {
        atomicAdd(commit_out, (sc[0] + sc[1] + sc[2] + sc[3]) * inv);
        atomicAdd(vq_out, (sv[0] + sv[1] + sv[2] + sv[3]) * inv);
    }
}

extern "C" void kernel_launch(void* const* d_in, const int* in_sizes, int n_in,
                              void* d_out, int out_size, void* d_ws, size_t ws_size,
                              hipStream_t stream)
{
    const int CB_SIZES[3] = {2048, 4096, 4096};

    // ---- workspace layout (u32 units) ----
    unsigned* H1   = (unsigned*)d_ws;                  // 3 * B*256
    unsigned* H2   = H1 + (size_t)3 * BSZ * 256;       // 3 * B*256
    unsigned* ZEP  = H2 + (size_t)3 * BSZ * 256;       // 3 * B*64
    unsigned* ZQ   = ZEP + (size_t)3 * BSZ * 64;       // 3 * B*64
    unsigned* ATT  = ZQ + (size_t)3 * BSZ * 64;        // 2 * B*64
    float* cbn     = (float*)(ATT + (size_t)2 * BSZ * 64);  // 10240
    float* bd      = cbn + 10240;                      // 10 * BSZ
    int*   bi      = (int*)(bd + 10 * BSZ);            // 10 * BSZ
    unsigned* wcb  = (unsigned*)(bi + 10 * BSZ);       // 2*4096 fragged wcomb
    float* bcomb   = (float*)(wcb + 2 * 4096);         // 2*64
    unsigned* wp   = (unsigned*)(bcomb + 128);         // codebook interleaved planes

    float* out = (float*)d_out;
    float* vq_loss = out + (size_t)3 * BSZ * 512;
    float* commit  = vq_loss + 1;
    hipMemsetAsync(vq_loss, 0, 2 * sizeof(float), stream);

    // ---- prep: codebooks only -> interleaved planes (for merge_gather) ----
    PrepArgs pa; int pos = 0, ns = 0;
    const unsigned* cbp[3];
    auto add = [&](const float* src, int n) -> const unsigned* {
        pa.src[ns] = src; pa.dst[ns] = wp + pos; pa.start[ns] = pos;
        pos += n; ns++; return wp + pos - n;
    };
    for (int l = 0; l < 3; ++l)
        cbp[l] = add((const float*)d_in[3 + 13 * l + 12], CB_SIZES[l] * 64);
    pa.start[ns] = pos; pa.nseg = ns;
    for (int i = ns + 1; i < 24; ++i) pa.start[i] = 0x7fffffff;

    // fragged codebooks after wp
    unsigned short* cbf0 = (unsigned short*)(wp + pos);
    unsigned short* cbf1 = cbf0 + (size_t)2048 * 128;
    unsigned short* cbf2 = cbf1 + (size_t)4096 * 128;
    // fragged weights after codebook frags (10240*128 ushorts total above)
    unsigned short* wfr = (unsigned short*)(wp + pos + 655360);

    // ---- w_frag descriptor (slots = N*K/4: BOTH planes!) ----
    WFragArgs wa; int fpos = 0, wslot = 0;
    const unsigned short* wfp[3][6];
    auto addw = [&](const float* src, int Nn, int Kk, int kl) -> const unsigned short* {
        wa.src[wslot] = src; wa.dst[wslot] = wfr + (size_t)fpos * 8;
        wa.start[wslot] = fpos; wa.kslog[wslot] = kl;
        fpos += Nn * Kk / 4; wslot++;
        return wa.dst[wslot - 1];
    };
    for (int l = 0; l < 3; ++l) {
        const int base = 3 + 13 * l;
        wfp[l][0] = addw((const float*)d_in[base + 0], 256, 512, 4);
        wfp[l][1] = addw((const float*)d_in[base + 2], 256, 256, 3);
        wfp[l][2] = addw((const float*)d_in[base + 4], 64, 256, 3);
        wfp[l][3] = addw((const float*)d_in[base + 6], 256, 64, 1);
        wfp[l][4] = addw((const float*)d_in[base + 8], 256, 256, 3);
        wfp[l][5] = addw((const float*)d_in[base + 10], 512, 256, 3);
    }
    wa.start[18] = fpos;   // 319488

    hipLaunchKernelGGL(prep_kernel, dim3(pos >> 10), dim3(256), 0, stream, pa);
    hipLaunchKernelGGL(cb_norms3, dim3(40), dim3(256), 0, stream,
                       (const float*)d_in[15], (const float*)d_in[28], (const float*)d_in[41], cbn);
    hipLaunchKernelGGL(cb_frag3, dim3(640), dim3(256), 0, stream,
                       (const float*)d_in[15], (const float*)d_in[28], (const float*)d_in[41],
                       cbf0, cbf1, cbf2);
    hipLaunchKernelGGL(w_frag, dim3(fpos / 256), dim3(256), 0, stream, wa);
    for (int j = 0; j < 2; ++j)
        hipLaunchKernelGGL(attn_combine, dim3(1), dim3(256), 0, stream,
                           (const float*)d_in[42 + 4 * j], (const float*)d_in[42 + 4 * j + 1],
                           (const float*)d_in[42 + 4 * j + 2], (const float*)d_in[42 + 4 * j + 3],
                           wcb + j * 4096, bcomb + j * 64);

    // ---- encoders, batched over levels (split-bf16, fp32-grade) ----
    GemmB g;
    for (int l = 0; l < 3; ++l) {
        g.A[l] = d_in[l]; g.W[l] = wfp[l][0];
        g.bias[l] = (const float*)d_in[3 + 13 * l + 1];
        g.C[l] = H1 + (size_t)l * BSZ * 256;
    }
    hipLaunchKernelGGL((gemmb6<1, 128, 1, 1>), dim3(2, 256, 3), dim3(256), 0, stream,
                       g, BSZ, 256, 512, 1);
    for (int l = 0; l < 3; ++l) {
        g.A[l] = H1 + (size_t)l * BSZ * 256; g.W[l] = wfp[l][1];
        g.bias[l] = (const float*)d_in[3 + 13 * l + 3];
        g.C[l] = H2 + (size_t)l * BSZ * 256;
    }
    hipLaunchKernelGGL((gemmb6<1, 128, 0, 1>), dim3(2, 256, 3), dim3(256), 0, stream,
                       g, BSZ, 256, 256, 1);
    for (int l = 0; l < 3; ++l) {
        g.A[l] = H2 + (size_t)l * BSZ * 256; g.W[l] = wfp[l][2];
        g.bias[l] = (const float*)d_in[3 + 13 * l + 5];
        g.C[l] = ZEP + (size_t)l * BSZ * 64;
    }
    hipLaunchKernelGGL((gemmb6<1, 64, 0, 1>), dim3(1, 256, 3), dim3(256), 0, stream,
                       g, BSZ, 64, 256, 0);

    // ---- VQ: 10 chunks of 1024 entries (l0:2, l1:4, l2:4) ----
    VqB2 vb;
    {
        const unsigned short* cbfl[3] = {cbf0, cbf1, cbf2};
        int c = 0;
        for (int l = 0; l < 3; ++l) {
            const int nch = CB_SIZES[l] / 1024;
            const int cb_off = (l == 0) ? 0 : (l == 1 ? 2048 : 6144);
            for (int k = 0; k < nch; ++k, ++c) {
                vb.zep[c] = ZEP + (size_t)l * BSZ * 64;
                vb.cbf[c] = cbfl[l];
                vb.cbn[c] = cbn + cb_off;
                vb.e_base[c] = k * 1024;
            }
        }
    }
    hipLaunchKernelGGL(vq_sweep2, dim3(BSZ / 128, 10), dim3(256), 0, stream, vb, bd, bi);
    hipLaunchKernelGGL(merge_gather_b, dim3(3 * BSZ * 64 / 256), dim3(256), 0, stream,
                       bd, bi, cbp[0], cbp[1], cbp[2], ZQ);

    // ---- folded attention (loss-only), batched over 2 ----
    for (int j = 0; j < 2; ++j) {
        g.A[j] = ZQ + (size_t)j * BSZ * 64;
        g.W[j] = (const unsigned short*)(wcb + j * 4096);
        g.bias[j] = bcomb + j * 64;
        g.C[j] = ATT + (size_t)j * BSZ * 64;
    }
    g.A[2] = g.A[1]; g.W[2] = g.W[1]; g.bias[2] = g.bias[1]; g.C[2] = g.C[1];
    hipLaunchKernelGGL((gemmb6<0, 64, 0, 1>), dim3(1, 256, 2), dim3(256), 0, stream,
                       g, BSZ, 64, 64, 0);

    // ---- losses, batched over 3 ----
    hipLaunchKernelGGL(loss_b, dim3(256, 1, 3), dim3(256), 0, stream,
                       ZEP, ZQ, ATT, vq_loss, commit, 1.0f / (float)(BSZ * 64));

    // ---- decoders, batched over levels (plain bf16) ----
    for (int l = 0; l < 3; ++l) {
        g.A[l] = ZQ + (size_t)l * BSZ * 64; g.W[l] = wfp[l][3];
        g.bias[l] = (const float*)d_in[3 + 13 * l + 7];
        g.C[l] = H1 + (size_t)l * BSZ * 256;
    }
    hipLaunchKernelGGL((gemmb6<0, 128, 0, 1>), dim3(2, 256, 3), dim3(256), 0, stream,
                       g, BSZ, 256, 64, 1);
    for (int l = 0; l < 3; ++l) {
        g.A[l] = H1 + (size_t)l * BSZ * 256; g.W[l] = wfp[l][4];
        g.bias[l] = (const float*)d_in[3 + 13 * l + 9];
        g.C[l] = H2 + (size_t)l * BSZ * 256;
    }
    hipLaunchKernelGGL((gemmb6<0, 128, 0, 1>), dim3(2, 256, 3), dim3(256), 0, stream,
                       g, BSZ, 256, 256, 1);
    for (int l = 0; l < 3; ++l) {
        g.A[l] = H2 + (size_t)l * BSZ * 256; g.W[l] = wfp[l][5];
        g.bias[l] = (const float*)d_in[3 + 13 * l + 11];
        g.C[l] = out + (size_t)l * BSZ * 512;
    }
    hipLaunchKernelGGL((gemmb6<0, 128, 0, 0>), dim3(4, 256, 3), dim3(256), 0, stream,
                       g, BSZ, 512, 256, 0);
}